// Round 3
// baseline (384.939 us; speedup 1.0000x reference)
//
#include <hip/hip_runtime.h>

// out[s][o] = sum_i x[s][i] * dq(w[o][i]); int4 group quant, group=256, scale=max(absmax/7,1e-9)
// x: [16,4096] f32, w: [14336,4096] f32, out: [16,14336] f32
//
// R3: in-block split-K(2) -> 7168 waves (2x occupancy); 63-shuffle value-split
// epilogue reduction; clamp dropped (provably dead: |w*invs| <= 7); rcp fast.

constexpr int O_DIM = 14336;
constexpr int I_DIM = 4096;
constexpr int S_DIM = 16;
constexpr int GS    = 256;            // quant group size
constexpr int NSPL  = 2;              // i-splits per block (wave pairs)
constexpr int GPS   = (I_DIM / GS) / NSPL;  // 8 groups per split
constexpr int RPW   = 4;              // rows per wave
constexpr int RPB   = 8;              // rows per block (2 row-waves x 4)

__global__ __launch_bounds__(256, 4)
void qlin_kernel(const float* __restrict__ x,
                 const float* __restrict__ w,
                 float* __restrict__ out)
{
    __shared__ float part[NSPL - 1][2][64];   // hi-split partials: [1][rowwave][lane]

    const int tid  = threadIdx.x;
    const int lane = tid & 63;
    const int wv   = tid >> 6;        // 0..3
    const int rw   = wv & 1;          // which 4-row group
    const int sp   = wv >> 1;         // which i-half
    const int row0 = blockIdx.x * RPB + rw * RPW;
    const size_t ibase = (size_t)sp * (I_DIM / NSPL);

    const float* wp = w + (size_t)row0 * I_DIM + ibase + lane * 4;
    const float* xp = x + ibase + lane * 4;

    float acc[RPW][S_DIM];
#pragma unroll
    for (int r = 0; r < RPW; ++r)
#pragma unroll
        for (int s = 0; s < S_DIM; ++s) acc[r][s] = 0.0f;

    float4 wcur[RPW], wnext[RPW];
#pragma unroll
    for (int r = 0; r < RPW; ++r)
        wcur[r] = *reinterpret_cast<const float4*>(wp + (size_t)r * I_DIM);

    for (int g = 0; g < GPS; ++g) {
        const int base = g * GS;

        // next group's w first (longest latency), stays in flight all iter
        if (g + 1 < GPS) {
#pragma unroll
            for (int r = 0; r < RPW; ++r)
                wnext[r] = *reinterpret_cast<const float4*>(
                    wp + (size_t)r * I_DIM + base + GS);
        }

        // x batch 0 (L1/L2-hit)
        float4 xv[4], xn[4];
#pragma unroll
        for (int k = 0; k < 4; ++k)
            xv[k] = *reinterpret_cast<const float4*>(xp + (size_t)k * I_DIM + base);

        // dequant: group absmax via 6-step butterfly (4 independent row chains)
        float4 dq[RPW];
#pragma unroll
        for (int r = 0; r < RPW; ++r) {
            float4 v = wcur[r];
            float m = fmaxf(fmaxf(fabsf(v.x), fabsf(v.y)),
                            fmaxf(fabsf(v.z), fabsf(v.w)));
#pragma unroll
            for (int off = 1; off < 64; off <<= 1)
                m = fmaxf(m, __shfl_xor(m, off, 64));
            float scale = fmaxf(m * (1.0f / 7.0f), 1e-9f);
            float invs  = __builtin_amdgcn_rcpf(scale);
            // clamp dead: scale >= absmax/7  =>  |v*invs| <= 7
            dq[r].x = rintf(v.x * invs) * scale;
            dq[r].y = rintf(v.y * invs) * scale;
            dq[r].z = rintf(v.z * invs) * scale;
            dq[r].w = rintf(v.w * invs) * scale;
        }

        // FMA over 16 s, register-double-buffered x batches of 4
#pragma unroll
        for (int sb = 0; sb < S_DIM; sb += 4) {
            if (sb + 4 < S_DIM) {
#pragma unroll
                for (int k = 0; k < 4; ++k)
                    xn[k] = *reinterpret_cast<const float4*>(
                        xp + (size_t)(sb + 4 + k) * I_DIM + base);
            }
#pragma unroll
            for (int k = 0; k < 4; ++k) {
                const int s = sb + k;
#pragma unroll
                for (int r = 0; r < RPW; ++r) {
                    acc[r][s] = fmaf(dq[r].x, xv[k].x, acc[r][s]);
                    acc[r][s] = fmaf(dq[r].y, xv[k].y, acc[r][s]);
                    acc[r][s] = fmaf(dq[r].z, xv[k].z, acc[r][s]);
                    acc[r][s] = fmaf(dq[r].w, xv[k].w, acc[r][s]);
                }
            }
#pragma unroll
            for (int k = 0; k < 4; ++k) xv[k] = xn[k];
        }

#pragma unroll
        for (int r = 0; r < RPW; ++r) wcur[r] = wnext[r];
    }

    // ---- epilogue: reduce 64 values across 64 lanes in 63 shuffles ----
    // value-splitting butterfly: each step halves values/lane;
    // lane l ends holding the full sum of value v = l = (r<<4)|s.
    float a[64];
#pragma unroll
    for (int r = 0; r < RPW; ++r)
#pragma unroll
        for (int s = 0; s < S_DIM; ++s) a[(r << 4) | s] = acc[r][s];

#pragma unroll
    for (int m = 32; m >= 1; m >>= 1) {
        const bool hi = (lane & m) != 0;
#pragma unroll
        for (int j = 0; j < m; ++j) {
            float snd  = hi ? a[j] : a[j + m];
            float rcv  = __shfl_xor(snd, m, 64);
            float kept = hi ? a[j + m] : a[j];
            a[j] = kept + rcv;
        }
    }
    float v = a[0];

    // combine the two i-halves via LDS (single barrier), waves 0/1 store
    if (sp == 1) part[0][rw][lane] = v;
    __syncthreads();
    if (sp == 0) {
        v += part[0][rw][lane];
        const int r = lane >> 4, s = lane & 15;
        out[s * O_DIM + (row0 + r)] = v;
    }
}

extern "C" void kernel_launch(void* const* d_in, const int* in_sizes, int n_in,
                              void* d_out, int out_size, void* d_ws, size_t ws_size,
                              hipStream_t stream) {
    const float* x = (const float*)d_in[0];   // 1*16*4096
    const float* w = (const float*)d_in[1];   // 14336*4096
    float* out = (float*)d_out;               // 16*14336
    dim3 grid(O_DIM / RPB);                   // 1792 blocks x 4 waves = 7168 waves
    dim3 block(256);
    qlin_kernel<<<grid, block, 0, stream>>>(x, w, out);
}

// Round 4
// 339.898 us; speedup vs baseline: 1.1325x; 1.1325x over previous
//
#include <hip/hip_runtime.h>

// out[s][o] = sum_i x[s][i] * dq(w[o][i]); int4 group quant, group=256, scale=max(absmax/7,1e-9)
// x: [16,4096] f32, w: [14336,4096] f32 (235 MB streamed once), out: [16,14336] f32
//
// R4: kill the false vmcnt dependency. x lives in LDS (staged in 4 phases of
// 1024 i = 64 KB), so the K-loop's global stream is w ONLY (vmcnt) and x reads
// are ds_read_b128 (lgkmcnt). FMA never waits on the in-flight wnext prefetch.
// 896-thr blocks (14 waves x 4 rows), grid=256 -> 1 block/CU, 14 waves/CU.

constexpr int O_DIM  = 14336;
constexpr int I_DIM  = 4096;
constexpr int S_DIM  = 16;
constexpr int GS     = 256;           // quant group size
constexpr int NG     = I_DIM / GS;    // 16 groups
constexpr int RPW    = 4;             // rows per wave
constexpr int NWAVE  = 14;            // waves per block
constexpr int RPB    = RPW * NWAVE;   // 56 rows/block; 14336/56 = 256 blocks
constexpr int PH_I   = 1024;          // i-extent per staging phase
constexpr int NPH    = I_DIM / PH_I;  // 4 phases
constexpr int GPP    = PH_I / GS;     // 4 groups per phase

__global__ __launch_bounds__(896)
void qlin_kernel(const float* __restrict__ x,
                 const float* __restrict__ w,
                 float* __restrict__ out)
{
    __shared__ float xs[S_DIM][PH_I];   // 64 KB

    const int tid  = threadIdx.x;
    const int lane = tid & 63;
    const int wv   = tid >> 6;          // 0..13
    const int row0 = blockIdx.x * RPB + wv * RPW;

    const float* wp = w + (size_t)row0 * I_DIM + lane * 4;

    float acc[RPW][S_DIM];
#pragma unroll
    for (int r = 0; r < RPW; ++r)
#pragma unroll
        for (int s = 0; s < S_DIM; ++s) acc[r][s] = 0.0f;

    float4 wcur[RPW], wnext[RPW];
#pragma unroll
    for (int r = 0; r < RPW; ++r)
        wcur[r] = *reinterpret_cast<const float4*>(wp + (size_t)r * I_DIM);

    for (int p = 0; p < NPH; ++p) {
        // ---- stage x[:, p*1024 .. +1024) into LDS (4096 float4 / 896 thr) ----
        for (int j = tid; j < S_DIM * (PH_I / 4); j += 896) {
            const int s  = j >> 8;          // /256 float4-per-row
            const int i4 = (j & 255) * 4;
            float4 v = *reinterpret_cast<const float4*>(
                &x[(size_t)s * I_DIM + p * PH_I + i4]);
            *reinterpret_cast<float4*>(&xs[s][i4]) = v;
        }
        __syncthreads();

        for (int g = 0; g < GPP; ++g) {
            const int G = p * GPP + g;      // global group index

            // w prefetch for next group — the ONLY vmem in the steady loop;
            // consumed next iteration, covered by dequant+FMA below.
            if (G + 1 < NG) {
#pragma unroll
                for (int r = 0; r < RPW; ++r)
                    wnext[r] = *reinterpret_cast<const float4*>(
                        wp + (size_t)r * I_DIM + (G + 1) * GS);
            }

            // dequant wcur in place (absmax butterfly; clamp provably dead)
#pragma unroll
            for (int r = 0; r < RPW; ++r) {
                float4 v = wcur[r];
                float m = fmaxf(fmaxf(fabsf(v.x), fabsf(v.y)),
                                fmaxf(fabsf(v.z), fabsf(v.w)));
#pragma unroll
                for (int off = 1; off < 64; off <<= 1)
                    m = fmaxf(m, __shfl_xor(m, off, 64));
                float scale = fmaxf(m * (1.0f / 7.0f), 1e-9f);
                float invs  = 1.0f / scale;
                wcur[r].x = rintf(v.x * invs) * scale;
                wcur[r].y = rintf(v.y * invs) * scale;
                wcur[r].z = rintf(v.z * invs) * scale;
                wcur[r].w = rintf(v.w * invs) * scale;
            }

            // FMA: x from LDS (lgkmcnt only — never waits on wnext)
            const int xb = g * GS + lane * 4;
#pragma unroll
            for (int s = 0; s < S_DIM; ++s) {
                float4 xv = *reinterpret_cast<const float4*>(&xs[s][xb]);
#pragma unroll
                for (int r = 0; r < RPW; ++r) {
                    acc[r][s] = fmaf(wcur[r].x, xv.x, acc[r][s]);
                    acc[r][s] = fmaf(wcur[r].y, xv.y, acc[r][s]);
                    acc[r][s] = fmaf(wcur[r].z, xv.z, acc[r][s]);
                    acc[r][s] = fmaf(wcur[r].w, xv.w, acc[r][s]);
                }
            }

#pragma unroll
            for (int r = 0; r < RPW; ++r) wcur[r] = wnext[r];
        }
        __syncthreads();   // all waves done reading phase p before restage
    }

    // ---- epilogue: reduce 64 accs across 64 lanes in 63 shuffles ----
    // value-splitting butterfly; lane l ends with the sum of a[l], l=(r<<4)|s.
    float a[64];
#pragma unroll
    for (int r = 0; r < RPW; ++r)
#pragma unroll
        for (int s = 0; s < S_DIM; ++s) a[(r << 4) | s] = acc[r][s];

#pragma unroll
    for (int m = 32; m >= 1; m >>= 1) {
        const bool hi = (lane & m) != 0;
#pragma unroll
        for (int j = 0; j < m; ++j) {
            float snd  = hi ? a[j] : a[j + m];
            float rcv  = __shfl_xor(snd, m, 64);
            float kept = hi ? a[j + m] : a[j];
            a[j] = kept + rcv;
        }
    }
    {
        const int r = lane >> 4, s = lane & 15;
        out[s * O_DIM + (row0 + r)] = a[0];
    }
}

extern "C" void kernel_launch(void* const* d_in, const int* in_sizes, int n_in,
                              void* d_out, int out_size, void* d_ws, size_t ws_size,
                              hipStream_t stream) {
    const float* x = (const float*)d_in[0];   // 1*16*4096
    const float* w = (const float*)d_in[1];   // 14336*4096
    float* out = (float*)d_out;               // 16*14336
    dim3 grid(O_DIM / RPB);                   // 256 blocks -> 1 per CU
    dim3 block(896);                          // 14 waves
    qlin_kernel<<<grid, block, 0, stream>>>(x, w, out);
}